// Round 6
// baseline (289.146 us; speedup 1.0000x reference)
//
#include <hip/hip_runtime.h>
#include <hip/hip_bf16.h>
#include <cstdint>
#include <cstddef>

#define B_  2
#define T_  4096
#define D_  768
#define H_  12
#define HD_ 64
#define M_  (B_*T_)   // 8192 rows

#define SCL 0.18033688f   // (1/sqrt(64)) * log2(e): folded into K projection

typedef __bf16 bf16x8 __attribute__((ext_vector_type(8)));
typedef float  f32x4  __attribute__((ext_vector_type(4)));
using bf16 = __hip_bfloat16;

__device__ inline float fexp2(float x) {
  float r; asm("v_exp_f32 %0, %1" : "=v"(r) : "v"(x)); return r;
}
__device__ inline uint32_t fu(float x) { union { float f; uint32_t u; } c; c.f = x; return c.u; }
__device__ inline uint32_t pktr(float a, float b) {   // truncated bf16 pair, 1 v_perm
  return __builtin_amdgcn_perm(fu(b), fu(a), 0x07060302);
}
#define GLD16(g, l) __builtin_amdgcn_global_load_lds( \
    (const __attribute__((address_space(1))) uint32_t*)(const void*)(g), \
    (__attribute__((address_space(3))) uint32_t*)(void*)(l), 16, 0, 0)

// ---------- fp32 -> bf16 cvt into MFMA-FRAGMENT-LINEAR order ----------------
// Layout per tensor: [tile16 rows][24 ktiles][64 lanes][8 bf16]; lane = qd*16+mi
// holds T[row = tile*16+mi][k = ktile*32 + qd*8 + i]. One GEMM fragment load is
// then base + lane*16 B — perfectly coalesced, no LDS needed in the GEMM.
__global__ void cvt_frag(const float* __restrict__ x,
                         const float* __restrict__ w0, const float* __restrict__ w1,
                         const float* __restrict__ w2, const float* __restrict__ w3,
                         bf16* __restrict__ xd,
                         bf16* __restrict__ d0, bf16* __restrict__ d1,
                         bf16* __restrict__ d2, bf16* __restrict__ d3) {
  const float* s; bf16* d; int n8;
  switch (blockIdx.y) {
    case 0: s = x;  d = xd; n8 = M_ * D_ / 8; break;
    case 1: s = w0; d = d0; n8 = D_ * D_ / 8; break;
    case 2: s = w1; d = d1; n8 = D_ * D_ / 8; break;
    case 3: s = w2; d = d2; n8 = D_ * D_ / 8; break;
    default: s = w3; d = d3; n8 = D_ * D_ / 8; break;
  }
  int i = blockIdx.x * blockDim.x + threadIdx.x;
  if (i >= n8) return;
  int row = i / 96, kg = i % 96;            // 8 k-elements per thread
  float4 v0 = ((const float4*)s)[i * 2];
  float4 v1 = ((const float4*)s)[i * 2 + 1];
  union { bf16 o[8]; uint4 u; } pk;
  pk.o[0] = __float2bfloat16(v0.x); pk.o[1] = __float2bfloat16(v0.y);
  pk.o[2] = __float2bfloat16(v0.z); pk.o[3] = __float2bfloat16(v0.w);
  pk.o[4] = __float2bfloat16(v1.x); pk.o[5] = __float2bfloat16(v1.y);
  pk.o[6] = __float2bfloat16(v1.z); pk.o[7] = __float2bfloat16(v1.w);
  size_t off = ((size_t)((row >> 4) * 24 + (kg >> 2)) * 64 + (kg & 3) * 16 + (row & 15)) * 8;
  *(uint4*)(d + off) = pk.u;
}

// ---------- barrier-free fragment-direct GEMM: C[M,N] = A[M,K] @ W[N,K]^T ----
// A (frag-order) and W (frag-order) streamed straight to VGPR fragments; the
// K-loop is MFMA <-> global_load interleaved with compiler vmcnt(N) — no LDS,
// no __syncthreads, latency hidden by waves + 1-deep frag double-buffer.
// z=0: Q out [B,T,D]; z=1: K*SCL out; z=2: V transposed out [B][D][T].
__global__ __launch_bounds__(256) void gemm_qkv(const bf16* __restrict__ A,
                                                const bf16* __restrict__ W0,
                                                const bf16* __restrict__ W1,
                                                const bf16* __restrict__ W2,
                                                bf16* __restrict__ O0,
                                                bf16* __restrict__ O1,
                                                bf16* __restrict__ O2t) {
  const int z = blockIdx.z;
  const bf16* Bw = (z == 0) ? W0 : ((z == 1) ? W1 : W2);
  const int t = threadIdx.x;
  const int w = t >> 6, lane = t & 63;
  const int wm = (w >> 1) * 64, wn = (w & 1) * 64;
  const int mi = lane & 15, qd = lane >> 4;
  const int m0 = blockIdx.y * 128, n0 = blockIdx.x * 128;

  const bf16* ap[4]; const bf16* bp[4];
  #pragma unroll
  for (int i = 0; i < 4; ++i) {
    int mtg = (m0 + wm) / 16 + i;
    int ntg = (n0 + wn) / 16 + i;
    ap[i] = A  + (size_t)mtg * 24 * 512 + lane * 8;
    bp[i] = Bw + (size_t)ntg * 24 * 512 + lane * 8;
  }

  f32x4 acc[4][4] = {};
  bf16x8 af[2][4], bf[2][4];
  #pragma unroll
  for (int i = 0; i < 4; ++i) {
    af[0][i] = *(const bf16x8*)(ap[i]);
    bf[0][i] = *(const bf16x8*)(bp[i]);
  }

  #pragma unroll 2
  for (int kk = 0; kk < 24; ++kk) {
    const int c = kk & 1;
    if (kk + 1 < 24) {
      #pragma unroll
      for (int i = 0; i < 4; ++i) {
        af[c ^ 1][i] = *(const bf16x8*)(ap[i] + (kk + 1) * 512);
        bf[c ^ 1][i] = *(const bf16x8*)(bp[i] + (kk + 1) * 512);
      }
    }
    #pragma unroll
    for (int mt = 0; mt < 4; ++mt)
      #pragma unroll
      for (int nt = 0; nt < 4; ++nt)
        acc[mt][nt] = __builtin_amdgcn_mfma_f32_16x16x32_bf16(af[c][mt], bf[c][nt], acc[mt][nt], 0, 0, 0);
  }

  const float scl = (z == 1) ? SCL : 1.0f;
  bf16* Ob = (z == 0) ? O0 : O1;
  #pragma unroll
  for (int mt = 0; mt < 4; ++mt) {
    #pragma unroll
    for (int nt = 0; nt < 4; ++nt) {
      int gr0 = m0 + wm + mt * 16 + qd * 4;
      int gc  = n0 + wn + nt * 16 + mi;
      if (z == 2) {
        union { bf16 o[4]; uint2 u; } pk;
        #pragma unroll
        for (int r = 0; r < 4; ++r) pk.o[r] = __float2bfloat16(acc[mt][nt][r]);
        int bb = gr0 >> 12, tt = gr0 & 4095;
        *(uint2*)(O2t + (size_t)bb * 768 * 4096 + (size_t)gc * 4096 + tt) = pk.u;
      } else {
        #pragma unroll
        for (int r = 0; r < 4; ++r)
          Ob[(size_t)(gr0 + r) * 768 + gc] = __float2bfloat16(acc[mt][nt][r] * scl);
      }
    }
  }
}

// ---------- output projection: ctx (natural layout, scattered frags) @ Wo^T ----
__global__ __launch_bounds__(256) void gemm_out(const bf16* __restrict__ A,
                                                const bf16* __restrict__ Bw,
                                                float* __restrict__ Cf,
                                                const float* __restrict__ bias) {
  const int t = threadIdx.x;
  const int w = t >> 6, lane = t & 63;
  const int wm = (w >> 1) * 64, wn = (w & 1) * 64;
  const int mi = lane & 15, qd = lane >> 4;
  const int m0 = blockIdx.y * 128, n0 = blockIdx.x * 128;

  const bf16* ap[4]; const bf16* bp[4];
  #pragma unroll
  for (int i = 0; i < 4; ++i) {
    ap[i] = A + (size_t)(m0 + wm + i * 16 + mi) * 768 + qd * 8;   // natural [M,K]
    int ntg = (n0 + wn) / 16 + i;
    bp[i] = Bw + (size_t)ntg * 24 * 512 + lane * 8;               // frag-order
  }

  f32x4 acc[4][4] = {};
  bf16x8 af[2][4], bf[2][4];
  #pragma unroll
  for (int i = 0; i < 4; ++i) {
    af[0][i] = *(const bf16x8*)(ap[i]);
    bf[0][i] = *(const bf16x8*)(bp[i]);
  }

  #pragma unroll 2
  for (int kk = 0; kk < 24; ++kk) {
    const int c = kk & 1;
    if (kk + 1 < 24) {
      #pragma unroll
      for (int i = 0; i < 4; ++i) {
        af[c ^ 1][i] = *(const bf16x8*)(ap[i] + (kk + 1) * 32);
        bf[c ^ 1][i] = *(const bf16x8*)(bp[i] + (kk + 1) * 512);
      }
    }
    #pragma unroll
    for (int mt = 0; mt < 4; ++mt)
      #pragma unroll
      for (int nt = 0; nt < 4; ++nt)
        acc[mt][nt] = __builtin_amdgcn_mfma_f32_16x16x32_bf16(af[c][mt], bf[c][nt], acc[mt][nt], 0, 0, 0);
  }

  #pragma unroll
  for (int mt = 0; mt < 4; ++mt)
    #pragma unroll
    for (int nt = 0; nt < 4; ++nt) {
      int gr0 = m0 + wm + mt * 16 + qd * 4;
      int gc  = n0 + wn + nt * 16 + mi;
      #pragma unroll
      for (int r = 0; r < 4; ++r)
        Cf[(size_t)(gr0 + r) * 768 + gc] = acc[mt][nt][r] + bias[gc];
    }
}

// ---------------- MFMA flash attention v4 (unchanged from R5) --------------------
__global__ __launch_bounds__(256) void flash_attn(const bf16* __restrict__ Q,
                                                  const bf16* __restrict__ K,
                                                  const bf16* __restrict__ Vt,
                                                  bf16* __restrict__ ctx) {
  __shared__ bf16 Ks[2][4096];
  __shared__ bf16 Vs[2][4096];
  __shared__ bf16 Pt[4][32 * 72];
  const int t = threadIdx.x;
  const int w = t >> 6, lane = t & 63;
  const int mi = lane & 15, qd = lane >> 4;
  const int bh   = blockIdx.x % 24;
  const int qrev = blockIdx.x / 24;           // heavy blocks (large q0) first
  const int q0 = T_ - 128 - qrev * 128;
  const int b = bh / H_, h = bh % H_;
  const size_t bTD = (size_t)b * T_ * D_;
  const char* Kp = (const char*)(K  + bTD + (size_t)h * HD_);
  const char* Vp = (const char*)(Vt + (size_t)b * D_ * T_ + (size_t)h * HD_ * T_);
  const int qwmin = q0 + w * 32;

  int vkoff[2], vvoff[2];
  #pragma unroll
  for (int i = 0; i < 2; ++i) {
    int s  = i * 64 + lane;
    int rl = s >> 3, cs = s & 7;
    int c  = cs ^ (rl & 7);
    vkoff[i] = (w * 16 + rl) * 1536 + c * 16;
    vvoff[i] = (w * 16 + rl) * 8192 + c * 16;
  }

  int fidx[4][2];
  #pragma unroll
  for (int jt = 0; jt < 4; ++jt)
    #pragma unroll
    for (int kt = 0; kt < 2; ++kt)
      fidx[jt][kt] = (jt * 16 + mi) * 64 + (((kt * 4 + qd) ^ (mi & 7)) * 8);

  bf16x8 qf[2][2];
  const bf16* Qp = Q + bTD + (size_t)h * HD_;
  #pragma unroll
  for (int qt = 0; qt < 2; ++qt)
    #pragma unroll
    for (int kt = 0; kt < 2; ++kt)
      qf[qt][kt] = *(const bf16x8*)(Qp + (size_t)(qwmin + qt * 16 + mi) * D_ + kt * 32 + qd * 8);

  f32x4 oacc[4][2] = {};
  float lst[2] = {0.f, 0.f};

  const int ntiles = q0 / 64 + 2;

  #pragma unroll
  for (int i = 0; i < 2; ++i) {
    GLD16(Kp + vkoff[i], &Ks[0][w * 1024 + i * 512]);
    GLD16(Vp + vvoff[i], &Vs[0][w * 1024 + i * 512]);
  }

  for (int tt = 0; tt < ntiles; ++tt) {
    __syncthreads();
    const int par = tt & 1;
    if (tt + 1 < ntiles) {
      const size_t j1 = (size_t)(tt + 1) * 64;
      const int np = par ^ 1;
      #pragma unroll
      for (int i = 0; i < 2; ++i) {
        GLD16(Kp + vkoff[i] + j1 * 1536, &Ks[np][w * 1024 + i * 512]);
        GLD16(Vp + vvoff[i] + j1 * 2,    &Vs[np][w * 1024 + i * 512]);
      }
    }
    const int j0 = tt * 64;
    if (j0 > qwmin + 31) continue;

    f32x4 sacc[4][2] = {};
    #pragma unroll
    for (int jt = 0; jt < 4; ++jt)
      #pragma unroll
      for (int kt = 0; kt < 2; ++kt) {
        bf16x8 kf = *(const bf16x8*)&Ks[par][fidx[jt][kt]];
        #pragma unroll
        for (int qt = 0; qt < 2; ++qt)
          sacc[jt][qt] = __builtin_amdgcn_mfma_f32_16x16x32_bf16(kf, qf[qt][kt], sacc[jt][qt], 0, 0, 0);
      }

    if (j0 + 63 > qwmin) {
      #pragma unroll
      for (int jt = 0; jt < 4; ++jt)
        #pragma unroll
        for (int qt = 0; qt < 2; ++qt) {
          int qg = qwmin + qt * 16 + mi;
          #pragma unroll
          for (int r = 0; r < 4; ++r) {
            int jg = j0 + jt * 16 + qd * 4 + r;
            if (jg > qg) sacc[jt][qt][r] = -1e30f;
          }
        }
    }

    #pragma unroll
    for (int jt = 0; jt < 4; ++jt)
      #pragma unroll
      for (int qt = 0; qt < 2; ++qt) {
        float p0 = fexp2(sacc[jt][qt][0]);
        float p1 = fexp2(sacc[jt][qt][1]);
        float p2 = fexp2(sacc[jt][qt][2]);
        float p3 = fexp2(sacc[jt][qt][3]);
        lst[qt] += (p0 + p1) + (p2 + p3);
        union { uint32_t u[2]; uint64_t d; } pw;
        pw.u[0] = pktr(p0, p1);
        pw.u[1] = pktr(p2, p3);
        *(uint64_t*)&Pt[w][(qt * 16 + mi) * 72 + jt * 16 + qd * 4] = pw.d;
      }

    bf16x8 vf[4][2];
    #pragma unroll
    for (int dt = 0; dt < 4; ++dt)
      #pragma unroll
      for (int kt = 0; kt < 2; ++kt)
        vf[dt][kt] = *(const bf16x8*)&Vs[par][fidx[dt][kt]];

    asm volatile("s_waitcnt lgkmcnt(0)" ::: "memory");

    #pragma unroll
    for (int ktp = 0; ktp < 2; ++ktp)
      #pragma unroll
      for (int qt = 0; qt < 2; ++qt) {
        bf16x8 pf = *(const bf16x8*)&Pt[w][(qt * 16 + mi) * 72 + ktp * 32 + qd * 8];
        #pragma unroll
        for (int dt = 0; dt < 4; ++dt)
          oacc[dt][qt] = __builtin_amdgcn_mfma_f32_16x16x32_bf16(vf[dt][ktp], pf, oacc[dt][qt], 0, 0, 0);
      }
  }

  #pragma unroll
  for (int qt = 0; qt < 2; ++qt) {
    float l = lst[qt];
    l += __shfl_xor(l, 16);
    l += __shfl_xor(l, 32);
    float inv = __builtin_amdgcn_rcpf(l);
    int qg = qwmin + qt * 16 + mi;
    bf16* cp = ctx + bTD + (size_t)qg * D_ + h * HD_ + qd * 4;
    #pragma unroll
    for (int dt = 0; dt < 4; ++dt) {
      union { bf16 o[4]; uint2 u; } pko;
      #pragma unroll
      for (int r = 0; r < 4; ++r) pko.o[r] = __float2bfloat16(oacc[dt][qt][r] * inv);
      *(uint2*)(cp + dt * 16) = pko.u;
    }
  }
}

// ---------------- launch ----------------
extern "C" void kernel_launch(void* const* d_in, const int* in_sizes, int n_in,
                              void* d_out, int out_size, void* d_ws, size_t ws_size,
                              hipStream_t stream) {
  const float* x  = (const float*)d_in[0];
  const float* Wq = (const float*)d_in[1];
  const float* Wk = (const float*)d_in[2];
  const float* Wv = (const float*)d_in[3];
  const float* Wo = (const float*)d_in[4];
  const float* bo = (const float*)d_in[5];
  float* out = (float*)d_out;

  char* ws = (char*)d_ws;
  const size_t SZ  = (size_t)M_ * D_ * 2;
  const size_t WSZ = (size_t)D_ * D_ * 2;
  bf16* xb   = (bf16*)(ws);                 // frag-order
  bf16* Qb   = (bf16*)(ws + 1 * SZ);        // [B,T,D]
  bf16* Kb   = (bf16*)(ws + 2 * SZ);        // [B,T,D], pre-scaled by SCL
  bf16* Vtg  = (bf16*)(ws + 3 * SZ);        // [B][D][T]
  bf16* ctxb = (bf16*)(ws + 4 * SZ);        // [B,T,D]
  bf16* Wqb  = (bf16*)(ws + 5 * SZ);        // frag-order
  bf16* Wkb  = (bf16*)(ws + 5 * SZ + 1 * WSZ);
  bf16* Wvb  = (bf16*)(ws + 5 * SZ + 2 * WSZ);
  bf16* Wob  = (bf16*)(ws + 5 * SZ + 3 * WSZ);

  dim3 gcv(M_ * D_ / 8 / 256, 5);           // (3072, 5); weight slices exit early
  cvt_frag<<<gcv, 256, 0, stream>>>(x, Wq, Wk, Wv, Wo, xb, Wqb, Wkb, Wvb, Wob);

  dim3 gq(D_ / 128, M_ / 128, 3);
  gemm_qkv<<<gq, 256, 0, stream>>>(xb, Wqb, Wkb, Wvb, Qb, Kb, Vtg);

  flash_attn<<<(T_ / 128) * B_ * H_, 256, 0, stream>>>(Qb, Kb, Vtg, ctxb);

  dim3 gg(D_ / 128, M_ / 128);
  gemm_out<<<gg, 256, 0, stream>>>(ctxb, Wob, out, bo);
}

// Round 7
// 281.449 us; speedup vs baseline: 1.0273x; 1.0273x over previous
//
#include <hip/hip_runtime.h>
#include <hip/hip_bf16.h>
#include <cstdint>
#include <cstddef>

#define B_  2
#define T_  4096
#define D_  768
#define H_  12
#define HD_ 64
#define M_  (B_*T_)   // 8192 rows

#define SCL 0.18033688f   // (1/sqrt(64)) * log2(e): folded into K projection

typedef __bf16 bf16x8 __attribute__((ext_vector_type(8)));
typedef float  f32x4  __attribute__((ext_vector_type(4)));
typedef short  s16x4  __attribute__((ext_vector_type(4)));
using bf16 = __hip_bfloat16;

#define HAS_MFMA16 __has_builtin(__builtin_amdgcn_mfma_f32_16x16x16bf16_1k)

__device__ inline float fexp2(float x) {
  float r; asm("v_exp_f32 %0, %1" : "=v"(r) : "v"(x)); return r;
}
__device__ inline uint32_t fu(float x) { union { float f; uint32_t u; } c; c.f = x; return c.u; }
__device__ inline uint32_t pktr(float a, float b) {   // truncated bf16 pair, 1 v_perm
  return __builtin_amdgcn_perm(fu(b), fu(a), 0x07060302);
}
#define GLD16(g, l) __builtin_amdgcn_global_load_lds( \
    (const __attribute__((address_space(1))) uint32_t*)(const void*)(g), \
    (__attribute__((address_space(3))) uint32_t*)(void*)(l), 16, 0, 0)

// ---------------- fp32 -> bf16 conversion (x + 4 weights, exact 1D grid) ---------
__global__ void cvt_all(const float* __restrict__ x,
                        const float* __restrict__ w0, const float* __restrict__ w1,
                        const float* __restrict__ w2, const float* __restrict__ w3,
                        bf16* __restrict__ xd,
                        bf16* __restrict__ d0, bf16* __restrict__ d1,
                        bf16* __restrict__ d2, bf16* __restrict__ d3) {
  int blk = blockIdx.x;
  const float* s; bf16* d; int i;
  if (blk < 6144) {                       // x: 6144*256 == M*D/4 exactly
    s = x; d = xd; i = blk * 256 + threadIdx.x;
  } else {                                // weights: 576*256 == D*D/4 exactly
    int q = blk - 6144, which = q / 576, rb = q % 576;
    switch (which) {
      case 0: s = w0; d = d0; break;
      case 1: s = w1; d = d1; break;
      case 2: s = w2; d = d2; break;
      default: s = w3; d = d3; break;
    }
    i = rb * 256 + threadIdx.x;
  }
  float4 v = ((const float4*)s)[i];
  union { bf16 o[4]; uint2 u; } pk;
  pk.o[0] = __float2bfloat16(v.x); pk.o[1] = __float2bfloat16(v.y);
  pk.o[2] = __float2bfloat16(v.z); pk.o[3] = __float2bfloat16(v.w);
  *(uint2*)(d + 4 * (size_t)i) = pk.u;
}

// ---------------- m97-style GEMM (R5 staging) + swapped-operand epilogue ---------
// global_load_lds(16B) double-buffered, XOR-swizzled, one barrier per BK=32 iter.
// z=0 Q, z=1 K*SCL (MFMA operands SWAPPED -> C^T: quad = 4 consecutive features at
// one token -> packed uint2 stores); z=2 V unswapped -> transposed out [B][D][T].
__global__ __launch_bounds__(256) void gemm_qkv(const bf16* __restrict__ A,
                                                const bf16* __restrict__ W0,
                                                const bf16* __restrict__ W1,
                                                const bf16* __restrict__ W2,
                                                bf16* __restrict__ O0,
                                                bf16* __restrict__ O1,
                                                bf16* __restrict__ O2t) {
  __shared__ bf16 As[2][4096];
  __shared__ bf16 Bs[2][4096];
  const int z = blockIdx.z;
  const char* Bw = (const char*)((z == 0) ? W0 : ((z == 1) ? W1 : W2));
  const char* Ap = (const char*)A;
  const int t  = threadIdx.x;
  const int m0 = blockIdx.y * 128;
  const int n0 = blockIdx.x * 128;
  const int w = t >> 6, lane = t & 63;
  const int wm = (w >> 1) * 64, wn = (w & 1) * 64;
  const int mi = lane & 15, qd = lane >> 4;

  int aoff[2], boff[2];
  #pragma unroll
  for (int i = 0; i < 2; ++i) {
    int L = i * 256 + t;
    int row = L >> 2, sl = L & 3, c = sl ^ (row & 3);
    aoff[i] = (m0 + row) * 1536 + c * 16;
    boff[i] = (n0 + row) * 1536 + c * 16;
  }
  const int fsw = (qd ^ (mi & 3)) * 8;

  f32x4 acc[4][4] = {};

  #pragma unroll
  for (int i = 0; i < 2; ++i) {
    GLD16(Ap + aoff[i], &As[0][i * 2048 + w * 512]);
    GLD16(Bw + boff[i], &Bs[0][i * 2048 + w * 512]);
  }

  for (int kk = 0; kk < 24; ++kk) {
    __syncthreads();
    const int par = kk & 1;
    if (kk + 1 < 24) {
      const int np = par ^ 1, kb = (kk + 1) * 64;
      #pragma unroll
      for (int i = 0; i < 2; ++i) {
        GLD16(Ap + aoff[i] + kb, &As[np][i * 2048 + w * 512]);
        GLD16(Bw + boff[i] + kb, &Bs[np][i * 2048 + w * 512]);
      }
    }
    bf16x8 af[4], bfr[4];
    #pragma unroll
    for (int mt = 0; mt < 4; ++mt)
      af[mt] = *(const bf16x8*)&As[par][(wm + mt * 16 + mi) * 32 + fsw];
    #pragma unroll
    for (int nt = 0; nt < 4; ++nt)
      bfr[nt] = *(const bf16x8*)&Bs[par][(wn + nt * 16 + mi) * 32 + fsw];
    if (z == 2) {
      #pragma unroll
      for (int mt = 0; mt < 4; ++mt)
        #pragma unroll
        for (int nt = 0; nt < 4; ++nt)
          acc[mt][nt] = __builtin_amdgcn_mfma_f32_16x16x32_bf16(af[mt], bfr[nt], acc[mt][nt], 0, 0, 0);
    } else {  // swapped: C^T[f][t]
      #pragma unroll
      for (int mt = 0; mt < 4; ++mt)
        #pragma unroll
        for (int nt = 0; nt < 4; ++nt)
          acc[mt][nt] = __builtin_amdgcn_mfma_f32_16x16x32_bf16(bfr[nt], af[mt], acc[mt][nt], 0, 0, 0);
    }
  }

  if (z == 2) {
    // C[t][f]: quad holds 4 consecutive tokens at one feature -> V^T [B][D][T]
    #pragma unroll
    for (int mt = 0; mt < 4; ++mt)
      #pragma unroll
      for (int nt = 0; nt < 4; ++nt) {
        int gr0 = m0 + wm + mt * 16 + qd * 4;
        int gc  = n0 + wn + nt * 16 + mi;
        union { bf16 o[4]; uint2 u; } pk;
        #pragma unroll
        for (int r = 0; r < 4; ++r) pk.o[r] = __float2bfloat16(acc[mt][nt][r]);
        int bb = gr0 >> 12, tt = gr0 & 4095;
        *(uint2*)(O2t + (size_t)bb * 768 * 4096 + (size_t)gc * 4096 + tt) = pk.u;
      }
  } else {
    // C^T[f][t]: quad holds 4 consecutive features at one token -> packed store
    const float scl = (z == 1) ? SCL : 1.0f;
    bf16* Ob = (z == 0) ? O0 : O1;
    #pragma unroll
    for (int mt = 0; mt < 4; ++mt)
      #pragma unroll
      for (int nt = 0; nt < 4; ++nt) {
        int tkn = m0 + wm + mt * 16 + mi;
        int f0  = n0 + wn + nt * 16 + qd * 4;
        union { bf16 o[4]; uint2 u; } pk;
        #pragma unroll
        for (int r = 0; r < 4; ++r) pk.o[r] = __float2bfloat16(acc[mt][nt][r] * scl);
        *(uint2*)(Ob + (size_t)tkn * 768 + f0) = pk.u;
      }
  }
}

// ---------------- output projection (swapped operands -> float4 stores + bias) ----
__global__ __launch_bounds__(256) void gemm_out(const bf16* __restrict__ A,
                                                const bf16* __restrict__ Bw0,
                                                float* __restrict__ Cf,
                                                const float* __restrict__ bias) {
  __shared__ bf16 As[2][4096];
  __shared__ bf16 Bs[2][4096];
  const char* Ap = (const char*)A;
  const char* Bw = (const char*)Bw0;
  const int t  = threadIdx.x;
  const int m0 = blockIdx.y * 128;
  const int n0 = blockIdx.x * 128;
  const int w = t >> 6, lane = t & 63;
  const int wm = (w >> 1) * 64, wn = (w & 1) * 64;
  const int mi = lane & 15, qd = lane >> 4;

  int aoff[2], boff[2];
  #pragma unroll
  for (int i = 0; i < 2; ++i) {
    int L = i * 256 + t;
    int row = L >> 2, sl = L & 3, c = sl ^ (row & 3);
    aoff[i] = (m0 + row) * 1536 + c * 16;
    boff[i] = (n0 + row) * 1536 + c * 16;
  }
  const int fsw = (qd ^ (mi & 3)) * 8;

  f32x4 acc[4][4] = {};

  #pragma unroll
  for (int i = 0; i < 2; ++i) {
    GLD16(Ap + aoff[i], &As[0][i * 2048 + w * 512]);
    GLD16(Bw + boff[i], &Bs[0][i * 2048 + w * 512]);
  }

  for (int kk = 0; kk < 24; ++kk) {
    __syncthreads();
    const int par = kk & 1;
    if (kk + 1 < 24) {
      const int np = par ^ 1, kb = (kk + 1) * 64;
      #pragma unroll
      for (int i = 0; i < 2; ++i) {
        GLD16(Ap + aoff[i] + kb, &As[np][i * 2048 + w * 512]);
        GLD16(Bw + boff[i] + kb, &Bs[np][i * 2048 + w * 512]);
      }
    }
    bf16x8 af[4], bfr[4];
    #pragma unroll
    for (int mt = 0; mt < 4; ++mt)
      af[mt] = *(const bf16x8*)&As[par][(wm + mt * 16 + mi) * 32 + fsw];
    #pragma unroll
    for (int nt = 0; nt < 4; ++nt)
      bfr[nt] = *(const bf16x8*)&Bs[par][(wn + nt * 16 + mi) * 32 + fsw];
    #pragma unroll
    for (int mt = 0; mt < 4; ++mt)
      #pragma unroll
      for (int nt = 0; nt < 4; ++nt)
        acc[mt][nt] = __builtin_amdgcn_mfma_f32_16x16x32_bf16(bfr[nt], af[mt], acc[mt][nt], 0, 0, 0);
  }

  // C^T[f][t]: 4 consecutive features at one token -> float4 store with bias
  #pragma unroll
  for (int mt = 0; mt < 4; ++mt)
    #pragma unroll
    for (int nt = 0; nt < 4; ++nt) {
      int tkn = m0 + wm + mt * 16 + mi;
      int f0  = n0 + wn + nt * 16 + qd * 4;
      float4 bv = *(const float4*)&bias[f0];
      float4 o;
      o.x = acc[mt][nt][0] + bv.x; o.y = acc[mt][nt][1] + bv.y;
      o.z = acc[mt][nt][2] + bv.z; o.w = acc[mt][nt][3] + bv.w;
      *(float4*)&Cf[(size_t)tkn * 768 + f0] = o;
    }
}

// ---------------- MFMA flash attention v5: K=16 PV, no P round-trip --------------
// S^T C-layout (q=mi, j=qd*4+r) == 16x16x16 B-operand layout (n=mi, k=qd*4+i):
// exp2 results feed PV directly from registers. V^T frags: 16 ds_read_b64.
__global__ __launch_bounds__(256) void flash_attn(const bf16* __restrict__ Q,
                                                  const bf16* __restrict__ K,
                                                  const bf16* __restrict__ Vt,
                                                  bf16* __restrict__ ctx) {
  __shared__ bf16 Ks[2][4096];
  __shared__ bf16 Vs[2][4096];
#if !HAS_MFMA16
  __shared__ bf16 Pt[4][32 * 72];
#endif
  const int t = threadIdx.x;
  const int w = t >> 6, lane = t & 63;
  const int mi = lane & 15, qd = lane >> 4;
  const int bh   = blockIdx.x % 24;
  const int qrev = blockIdx.x / 24;           // heavy blocks (large q0) first
  const int q0 = T_ - 128 - qrev * 128;
  const int b = bh / H_, h = bh % H_;
  const size_t bTD = (size_t)b * T_ * D_;
  const char* Kp = (const char*)(K  + bTD + (size_t)h * HD_);
  const char* Vp = (const char*)(Vt + (size_t)b * D_ * T_ + (size_t)h * HD_ * T_);
  const int qwmin = q0 + w * 32;

  int vkoff[2], vvoff[2];
  #pragma unroll
  for (int i = 0; i < 2; ++i) {
    int s  = i * 64 + lane;
    int rl = s >> 3, cs = s & 7;
    int c  = cs ^ (rl & 7);
    vkoff[i] = (w * 16 + rl) * 1536 + c * 16;
    vvoff[i] = (w * 16 + rl) * 8192 + c * 16;
  }

  // K b128 fragment indices (QK^T): row jt*16+mi, chunk (kt*4+qd)^(mi&7)
  int fidx[4][2];
  #pragma unroll
  for (int jt = 0; jt < 4; ++jt)
    #pragma unroll
    for (int kt = 0; kt < 2; ++kt)
      fidx[jt][kt] = (jt * 16 + mi) * 64 + (((kt * 4 + qd) ^ (mi & 7)) * 8);

  // V b64 fragment indices (K=16 PV): row dt*16+mi, j = jt*16 + qd*4 .. +3
  int vidx[4][4];
  #pragma unroll
  for (int dt = 0; dt < 4; ++dt)
    #pragma unroll
    for (int jt = 0; jt < 4; ++jt)
      vidx[dt][jt] = (dt * 16 + mi) * 64 + ((2 * jt + (qd >> 1)) ^ (mi & 7)) * 8 + (qd & 1) * 4;

  bf16x8 qf[2][2];
  const bf16* Qp = Q + bTD + (size_t)h * HD_;
  #pragma unroll
  for (int qt = 0; qt < 2; ++qt)
    #pragma unroll
    for (int kt = 0; kt < 2; ++kt)
      qf[qt][kt] = *(const bf16x8*)(Qp + (size_t)(qwmin + qt * 16 + mi) * D_ + kt * 32 + qd * 8);

  f32x4 oacc[4][2] = {};
  float lst[2] = {0.f, 0.f};

  const int ntiles = q0 / 64 + 2;

  #pragma unroll
  for (int i = 0; i < 2; ++i) {
    GLD16(Kp + vkoff[i], &Ks[0][w * 1024 + i * 512]);
    GLD16(Vp + vvoff[i], &Vs[0][w * 1024 + i * 512]);
  }

  for (int tt = 0; tt < ntiles; ++tt) {
    __syncthreads();
    const int par = tt & 1;
    if (tt + 1 < ntiles) {
      const size_t j1 = (size_t)(tt + 1) * 64;
      const int np = par ^ 1;
      #pragma unroll
      for (int i = 0; i < 2; ++i) {
        GLD16(Kp + vkoff[i] + j1 * 1536, &Ks[np][w * 1024 + i * 512]);
        GLD16(Vp + vvoff[i] + j1 * 2,    &Vs[np][w * 1024 + i * 512]);
      }
    }
    const int j0 = tt * 64;
    if (j0 > qwmin + 31) continue;

    // S^T = K-tile @ Q^T  (C-layout: j = jt*16 + qd*4 + r, q = qt*16 + mi)
    f32x4 sacc[4][2] = {};
    #pragma unroll
    for (int jt = 0; jt < 4; ++jt)
      #pragma unroll
      for (int kt = 0; kt < 2; ++kt) {
        bf16x8 kf = *(const bf16x8*)&Ks[par][fidx[jt][kt]];
        #pragma unroll
        for (int qt = 0; qt < 2; ++qt)
          sacc[jt][qt] = __builtin_amdgcn_mfma_f32_16x16x32_bf16(kf, qf[qt][kt], sacc[jt][qt], 0, 0, 0);
      }

    if (j0 + 63 > qwmin) {                    // causal mask, diagonal tiles only
      #pragma unroll
      for (int jt = 0; jt < 4; ++jt)
        #pragma unroll
        for (int qt = 0; qt < 2; ++qt) {
          int qg = qwmin + qt * 16 + mi;
          #pragma unroll
          for (int r = 0; r < 4; ++r) {
            int jg = j0 + jt * 16 + qd * 4 + r;
            if (jg > qg) sacc[jt][qt][r] = -1e30f;
          }
        }
    }

    // p = exp2(s); per-lane partial l; pack bf16 pairs (PV B-op fragments)
    union { uint32_t u[2]; uint64_t d; s16x4 s; } pf[4][2];
    #pragma unroll
    for (int jt = 0; jt < 4; ++jt)
      #pragma unroll
      for (int qt = 0; qt < 2; ++qt) {
        float p0 = fexp2(sacc[jt][qt][0]);
        float p1 = fexp2(sacc[jt][qt][1]);
        float p2 = fexp2(sacc[jt][qt][2]);
        float p3 = fexp2(sacc[jt][qt][3]);
        lst[qt] += (p0 + p1) + (p2 + p3);
        pf[jt][qt].u[0] = pktr(p0, p1);
        pf[jt][qt].u[1] = pktr(p2, p3);
      }

#if HAS_MFMA16
    // O^T += V^T @ P^T via K=16 MFMA: P^T B-op == pf registers directly
    s16x4 vf4[4][4];
    #pragma unroll
    for (int dt = 0; dt < 4; ++dt)
      #pragma unroll
      for (int jt = 0; jt < 4; ++jt)
        vf4[dt][jt] = *(const s16x4*)&Vs[par][vidx[dt][jt]];
    #pragma unroll
    for (int qt = 0; qt < 2; ++qt)
      #pragma unroll
      for (int dt = 0; dt < 4; ++dt)
        #pragma unroll
        for (int jt = 0; jt < 4; ++jt)
          oacc[dt][qt] = __builtin_amdgcn_mfma_f32_16x16x16bf16_1k(vf4[dt][jt], pf[jt][qt].s, oacc[dt][qt], 0, 0, 0);
#else
    // fallback: per-wave LDS P round-trip (R5 path)
    #pragma unroll
    for (int jt = 0; jt < 4; ++jt)
      #pragma unroll
      for (int qt = 0; qt < 2; ++qt)
        *(uint64_t*)&Pt[w][(qt * 16 + mi) * 72 + jt * 16 + qd * 4] = pf[jt][qt].d;
    bf16x8 vf[4][2];
    #pragma unroll
    for (int dt = 0; dt < 4; ++dt)
      #pragma unroll
      for (int kt = 0; kt < 2; ++kt)
        vf[dt][kt] = *(const bf16x8*)&Vs[par][fidx[dt][kt]];
    asm volatile("s_waitcnt lgkmcnt(0)" ::: "memory");
    #pragma unroll
    for (int ktp = 0; ktp < 2; ++ktp)
      #pragma unroll
      for (int qt = 0; qt < 2; ++qt) {
        bf16x8 pfx = *(const bf16x8*)&Pt[w][(qt * 16 + mi) * 72 + ktp * 32 + qd * 8];
        #pragma unroll
        for (int dt = 0; dt < 4; ++dt)
          oacc[dt][qt] = __builtin_amdgcn_mfma_f32_16x16x32_bf16(vf[dt][ktp], pfx, oacc[dt][qt], 0, 0, 0);
      }
#endif
  }

  #pragma unroll
  for (int qt = 0; qt < 2; ++qt) {
    float l = lst[qt];
    l += __shfl_xor(l, 16);
    l += __shfl_xor(l, 32);
    float inv = __builtin_amdgcn_rcpf(l);
    int qg = qwmin + qt * 16 + mi;
    bf16* cp = ctx + bTD + (size_t)qg * D_ + h * HD_ + qd * 4;
    #pragma unroll
    for (int dt = 0; dt < 4; ++dt) {
      union { bf16 o[4]; uint2 u; } pko;
      #pragma unroll
      for (int r = 0; r < 4; ++r) pko.o[r] = __float2bfloat16(oacc[dt][qt][r] * inv);
      *(uint2*)(cp + dt * 16) = pko.u;
    }
  }
}

// ---------------- launch ----------------
extern "C" void kernel_launch(void* const* d_in, const int* in_sizes, int n_in,
                              void* d_out, int out_size, void* d_ws, size_t ws_size,
                              hipStream_t stream) {
  const float* x  = (const float*)d_in[0];
  const float* Wq = (const float*)d_in[1];
  const float* Wk = (const float*)d_in[2];
  const float* Wv = (const float*)d_in[3];
  const float* Wo = (const float*)d_in[4];
  const float* bo = (const float*)d_in[5];
  float* out = (float*)d_out;

  char* ws = (char*)d_ws;
  const size_t SZ  = (size_t)M_ * D_ * 2;
  const size_t WSZ = (size_t)D_ * D_ * 2;
  bf16* xb   = (bf16*)(ws);                 // [M, D]
  bf16* Qb   = (bf16*)(ws + 1 * SZ);        // [B,T,D]
  bf16* Kb   = (bf16*)(ws + 2 * SZ);        // [B,T,D], pre-scaled by SCL
  bf16* Vtg  = (bf16*)(ws + 3 * SZ);        // [B][D][T]
  bf16* ctxb = (bf16*)(ws + 4 * SZ);        // [B,T,D]
  bf16* Wqb  = (bf16*)(ws + 5 * SZ);
  bf16* Wkb  = (bf16*)(ws + 5 * SZ + 1 * WSZ);
  bf16* Wvb  = (bf16*)(ws + 5 * SZ + 2 * WSZ);
  bf16* Wob  = (bf16*)(ws + 5 * SZ + 3 * WSZ);

  cvt_all<<<6144 + 4 * 576, 256, 0, stream>>>(x, Wq, Wk, Wv, Wo, xb, Wqb, Wkb, Wvb, Wob);

  dim3 gq(D_ / 128, M_ / 128, 3);
  gemm_qkv<<<gq, 256, 0, stream>>>(xb, Wqb, Wkb, Wvb, Qb, Kb, Vtg);

  flash_attn<<<(T_ / 128) * B_ * H_, 256, 0, stream>>>(Qb, Kb, Vtg, ctxb);

  dim3 gg(D_ / 128, M_ / 128);
  gemm_out<<<gg, 256, 0, stream>>>(ctxb, Wob, out, bo);
}

// Round 8
// 246.088 us; speedup vs baseline: 1.1750x; 1.1437x over previous
//
#include <hip/hip_runtime.h>
#include <hip/hip_bf16.h>
#include <cstdint>
#include <cstddef>

#define B_  2
#define T_  4096
#define D_  768
#define H_  12
#define HD_ 64
#define M_  (B_*T_)   // 8192 rows

#define SCL 0.18033688f   // (1/sqrt(64)) * log2(e): folded into K projection

typedef __bf16 bf16x8 __attribute__((ext_vector_type(8)));
typedef float  f32x4  __attribute__((ext_vector_type(4)));
using bf16 = __hip_bfloat16;

__device__ inline float fexp2(float x) {
  float r; asm("v_exp_f32 %0, %1" : "=v"(r) : "v"(x)); return r;
}
__device__ inline uint32_t fu(float x) { union { float f; uint32_t u; } c; c.f = x; return c.u; }
__device__ inline uint32_t pktr(float a, float b) {   // truncated bf16 pair, 1 v_perm
  return __builtin_amdgcn_perm(fu(b), fu(a), 0x07060302);
}
#define GLD16(g, l) __builtin_amdgcn_global_load_lds( \
    (const __attribute__((address_space(1))) uint32_t*)(const void*)(g), \
    (__attribute__((address_space(3))) uint32_t*)(void*)(l), 16, 0, 0)

// ---------------- fp32 -> bf16 conversion (x + 4 weights, exact 1D grid) ---------
__global__ void cvt_all(const float* __restrict__ x,
                        const float* __restrict__ w0, const float* __restrict__ w1,
                        const float* __restrict__ w2, const float* __restrict__ w3,
                        bf16* __restrict__ xd,
                        bf16* __restrict__ d0, bf16* __restrict__ d1,
                        bf16* __restrict__ d2, bf16* __restrict__ d3) {
  int blk = blockIdx.x;
  const float* s; bf16* d; int i;
  if (blk < 6144) {                       // x: 6144*256 == M*D/4 exactly
    s = x; d = xd; i = blk * 256 + threadIdx.x;
  } else {                                // weights: 576*256 == D*D/4 exactly
    int q = blk - 6144, which = q / 576, rb = q % 576;
    switch (which) {
      case 0: s = w0; d = d0; break;
      case 1: s = w1; d = d1; break;
      case 2: s = w2; d = d2; break;
      default: s = w3; d = d3; break;
    }
    i = rb * 256 + threadIdx.x;
  }
  float4 v = ((const float4*)s)[i];
  union { bf16 o[4]; uint2 u; } pk;
  pk.o[0] = __float2bfloat16(v.x); pk.o[1] = __float2bfloat16(v.y);
  pk.o[2] = __float2bfloat16(v.z); pk.o[3] = __float2bfloat16(v.w);
  *(uint2*)(d + 4 * (size_t)i) = pk.u;
}

// ---------------- unified QKV GEMM, single K-loop path ---------------------------
// Operand-role swap at STAGING: z=0/1 stage weight rows into As, x rows into Bs
// (C = [feature][token] -> packed per-token stores); z=2 stages x into As, Wv
// into Bs (C = [token][feature] -> V^T [B][D][T] stores). The unrolled K-loop
// (GLD16 dbuf, XOR swizzle, mfma(af,bfr)) is IDENTICAL for all z.
// 1D grid 1152, token-tile-major: the 18 blocks sharing an x panel are adjacent
// (XCD L2 reuse); per-XCD weight working set 18 panels ~3.4MB fits 4MiB L2.
__global__ __launch_bounds__(256) void gemm_qkv(const bf16* __restrict__ x,
                                                const bf16* __restrict__ W0,
                                                const bf16* __restrict__ W1,
                                                const bf16* __restrict__ W2,
                                                bf16* __restrict__ O0,
                                                bf16* __restrict__ O1,
                                                bf16* __restrict__ O2t) {
  __shared__ bf16 As[2][4096];
  __shared__ bf16 Bs[2][4096];
  const int flat = blockIdx.x;
  const int by = flat / 18;            // token tile (m)
  const int rr = flat % 18;
  const int z  = rr / 6;
  const int bx = rr % 6;               // feature tile (n)
  const bf16* Wz = (z == 0) ? W0 : ((z == 1) ? W1 : W2);
  const char* Ap; const char* Bp; int a0, b0;
  if (z == 2) { Ap = (const char*)x;  a0 = by * 128; Bp = (const char*)Wz; b0 = bx * 128; }
  else        { Ap = (const char*)Wz; a0 = bx * 128; Bp = (const char*)x;  b0 = by * 128; }
  const int t = threadIdx.x;
  const int w = t >> 6, lane = t & 63;
  const int wa = (w >> 1) * 64, wb = (w & 1) * 64;
  const int mi = lane & 15, qd = lane >> 4;

  int aoff[2], boff[2];
  #pragma unroll
  for (int i = 0; i < 2; ++i) {
    int L = i * 256 + t;
    int row = L >> 2, sl = L & 3, c = sl ^ (row & 3);
    aoff[i] = (a0 + row) * 1536 + c * 16;
    boff[i] = (b0 + row) * 1536 + c * 16;
  }
  const int fsw = (qd ^ (mi & 3)) * 8;

  f32x4 acc[4][4] = {};

  #pragma unroll
  for (int i = 0; i < 2; ++i) {
    GLD16(Ap + aoff[i], &As[0][i * 2048 + w * 512]);
    GLD16(Bp + boff[i], &Bs[0][i * 2048 + w * 512]);
  }

  for (int kk = 0; kk < 24; ++kk) {
    __syncthreads();
    const int par = kk & 1;
    if (kk + 1 < 24) {
      const int np = par ^ 1, kb = (kk + 1) * 64;
      #pragma unroll
      for (int i = 0; i < 2; ++i) {
        GLD16(Ap + aoff[i] + kb, &As[np][i * 2048 + w * 512]);
        GLD16(Bp + boff[i] + kb, &Bs[np][i * 2048 + w * 512]);
      }
    }
    bf16x8 af[4], bfr[4];
    #pragma unroll
    for (int at = 0; at < 4; ++at)
      af[at] = *(const bf16x8*)&As[par][(wa + at * 16 + mi) * 32 + fsw];
    #pragma unroll
    for (int bt = 0; bt < 4; ++bt)
      bfr[bt] = *(const bf16x8*)&Bs[par][(wb + bt * 16 + mi) * 32 + fsw];
    #pragma unroll
    for (int at = 0; at < 4; ++at)
      #pragma unroll
      for (int bt = 0; bt < 4; ++bt)
        acc[at][bt] = __builtin_amdgcn_mfma_f32_16x16x32_bf16(af[at], bfr[bt], acc[at][bt], 0, 0, 0);
  }

  // C layout: A-row (local) = qd*4+r, B-row = mi
  if (z == 2) {
    // A rows = tokens, B rows = features -> V^T [B][D][T], uint2 over 4 tokens
    #pragma unroll
    for (int at = 0; at < 4; ++at)
      #pragma unroll
      for (int bt = 0; bt < 4; ++bt) {
        int gr = a0 + wa + at * 16 + qd * 4;          // token
        int gc = b0 + wb + bt * 16 + mi;              // feature
        union { bf16 o[4]; uint2 u; } pk;
        #pragma unroll
        for (int r = 0; r < 4; ++r) pk.o[r] = __float2bfloat16(acc[at][bt][r]);
        int bb = gr >> 12, tt = gr & 4095;
        *(uint2*)(O2t + (size_t)bb * 768 * 4096 + (size_t)gc * 4096 + tt) = pk.u;
      }
  } else {
    // A rows = features, B rows = tokens -> packed uint2 per token
    const float scl = (z == 1) ? SCL : 1.0f;
    bf16* Ob = (z == 0) ? O0 : O1;
    #pragma unroll
    for (int at = 0; at < 4; ++at)
      #pragma unroll
      for (int bt = 0; bt < 4; ++bt) {
        int f0  = a0 + wa + at * 16 + qd * 4;
        int tkn = b0 + wb + bt * 16 + mi;
        union { bf16 o[4]; uint2 u; } pk;
        #pragma unroll
        for (int r = 0; r < 4; ++r) pk.o[r] = __float2bfloat16(acc[at][bt][r] * scl);
        *(uint2*)(Ob + (size_t)tkn * 768 + f0) = pk.u;
      }
  }
}

// ---------------- output projection (Wo staged as A -> float4 stores + bias) -----
__global__ __launch_bounds__(256) void gemm_out(const bf16* __restrict__ ctx,
                                                const bf16* __restrict__ Wo,
                                                float* __restrict__ Cf,
                                                const float* __restrict__ bias) {
  __shared__ bf16 As[2][4096];
  __shared__ bf16 Bs[2][4096];
  const int flat = blockIdx.x;
  const int by = flat / 6, bx = flat % 6;
  const char* Ap = (const char*)Wo;  const int a0 = bx * 128;   // feature rows
  const char* Bp = (const char*)ctx; const int b0 = by * 128;   // token rows
  const int t = threadIdx.x;
  const int w = t >> 6, lane = t & 63;
  const int wa = (w >> 1) * 64, wb = (w & 1) * 64;
  const int mi = lane & 15, qd = lane >> 4;

  int aoff[2], boff[2];
  #pragma unroll
  for (int i = 0; i < 2; ++i) {
    int L = i * 256 + t;
    int row = L >> 2, sl = L & 3, c = sl ^ (row & 3);
    aoff[i] = (a0 + row) * 1536 + c * 16;
    boff[i] = (b0 + row) * 1536 + c * 16;
  }
  const int fsw = (qd ^ (mi & 3)) * 8;

  f32x4 acc[4][4] = {};

  #pragma unroll
  for (int i = 0; i < 2; ++i) {
    GLD16(Ap + aoff[i], &As[0][i * 2048 + w * 512]);
    GLD16(Bp + boff[i], &Bs[0][i * 2048 + w * 512]);
  }

  for (int kk = 0; kk < 24; ++kk) {
    __syncthreads();
    const int par = kk & 1;
    if (kk + 1 < 24) {
      const int np = par ^ 1, kb = (kk + 1) * 64;
      #pragma unroll
      for (int i = 0; i < 2; ++i) {
        GLD16(Ap + aoff[i] + kb, &As[np][i * 2048 + w * 512]);
        GLD16(Bp + boff[i] + kb, &Bs[np][i * 2048 + w * 512]);
      }
    }
    bf16x8 af[4], bfr[4];
    #pragma unroll
    for (int at = 0; at < 4; ++at)
      af[at] = *(const bf16x8*)&As[par][(wa + at * 16 + mi) * 32 + fsw];
    #pragma unroll
    for (int bt = 0; bt < 4; ++bt)
      bfr[bt] = *(const bf16x8*)&Bs[par][(wb + bt * 16 + mi) * 32 + fsw];
    #pragma unroll
    for (int at = 0; at < 4; ++at)
      #pragma unroll
      for (int bt = 0; bt < 4; ++bt)
        acc[at][bt] = __builtin_amdgcn_mfma_f32_16x16x32_bf16(af[at], bfr[bt], acc[at][bt], 0, 0, 0);
  }

  #pragma unroll
  for (int at = 0; at < 4; ++at)
    #pragma unroll
    for (int bt = 0; bt < 4; ++bt) {
      int f0  = a0 + wa + at * 16 + qd * 4;
      int tkn = b0 + wb + bt * 16 + mi;
      float4 bv = *(const float4*)&bias[f0];
      float4 o;
      o.x = acc[at][bt][0] + bv.x; o.y = acc[at][bt][1] + bv.y;
      o.z = acc[at][bt][2] + bv.z; o.w = acc[at][bt][3] + bv.w;
      *(float4*)&Cf[(size_t)tkn * 768 + f0] = o;
    }
}

// ---------------- MFMA flash attention v6: 8 waves x 16 Q-rows -------------------
// Same 64-key dbuf GLD tiles; per-wave work halved, waves/SIMD 3 -> 4+ for
// latency hiding; finer 16-row diagonal skip; PV = K=32 MFMA via per-wave LDS P.
__global__ __launch_bounds__(512, 4) void flash_attn(const bf16* __restrict__ Q,
                                                     const bf16* __restrict__ K,
                                                     const bf16* __restrict__ Vt,
                                                     bf16* __restrict__ ctx) {
  __shared__ bf16 Ks[2][4096];
  __shared__ bf16 Vs[2][4096];
  __shared__ bf16 Pt[8][16 * 72];
  const int t = threadIdx.x;
  const int w = t >> 6, lane = t & 63;
  const int mi = lane & 15, qd = lane >> 4;
  const int bh   = blockIdx.x % 24;
  const int qrev = blockIdx.x / 24;           // heavy blocks (large q0) first
  const int q0 = T_ - 128 - qrev * 128;
  const int b = bh / H_, h = bh % H_;
  const size_t bTD = (size_t)b * T_ * D_;
  const char* Kp = (const char*)(K  + bTD + (size_t)h * HD_);
  const char* Vp = (const char*)(Vt + (size_t)b * D_ * T_ + (size_t)h * HD_ * T_);
  const int qw = q0 + w * 16;                 // wave's 16 q-rows

  // staging: 1 K-chunk + 1 V-chunk per thread (512 thr x 16B = full 64x64 tile)
  const int rl = t >> 3, c = (t & 7) ^ (rl & 7);
  const int vkoff = rl * 1536 + c * 16;
  const int vvoff = rl * 8192 + c * 16;

  int fidx[4][2];
  #pragma unroll
  for (int jt = 0; jt < 4; ++jt)
    #pragma unroll
    for (int kt = 0; kt < 2; ++kt)
      fidx[jt][kt] = (jt * 16 + mi) * 64 + (((kt * 4 + qd) ^ (mi & 7)) * 8);

  bf16x8 qf[2];
  const bf16* Qp = Q + bTD + (size_t)h * HD_;
  #pragma unroll
  for (int kt = 0; kt < 2; ++kt)
    qf[kt] = *(const bf16x8*)(Qp + (size_t)(qw + mi) * D_ + kt * 32 + qd * 8);

  f32x4 oacc[4] = {};
  float lst = 0.f;
  const int ntiles = q0 / 64 + 2;

  GLD16(Kp + vkoff, &Ks[0][w * 512]);
  GLD16(Vp + vvoff, &Vs[0][w * 512]);

  for (int tt = 0; tt < ntiles; ++tt) {
    __syncthreads();
    const int par = tt & 1;
    if (tt + 1 < ntiles) {
      const size_t j1 = (size_t)(tt + 1) * 64;
      const int np = par ^ 1;
      GLD16(Kp + vkoff + j1 * 1536, &Ks[np][w * 512]);
      GLD16(Vp + vvoff + j1 * 2,    &Vs[np][w * 512]);
    }
    const int j0 = tt * 64;
    if (j0 > qw + 15) continue;               // fully masked for this wave

    // S^T = K-tile @ Q^T  (C-layout: j = jt*16 + qd*4 + r, q = mi)
    f32x4 sacc[4] = {};
    #pragma unroll
    for (int jt = 0; jt < 4; ++jt)
      #pragma unroll
      for (int kt = 0; kt < 2; ++kt) {
        bf16x8 kf = *(const bf16x8*)&Ks[par][fidx[jt][kt]];
        sacc[jt] = __builtin_amdgcn_mfma_f32_16x16x32_bf16(kf, qf[kt], sacc[jt], 0, 0, 0);
      }

    if (j0 + 63 > qw) {                       // causal mask, diagonal tiles only
      const int qg = qw + mi;
      #pragma unroll
      for (int jt = 0; jt < 4; ++jt)
        #pragma unroll
        for (int r = 0; r < 4; ++r) {
          int jg = j0 + jt * 16 + qd * 4 + r;
          if (jg > qg) sacc[jt][r] = -1e30f;
        }
    }

    // p = exp2(s); per-lane partial l; P[q][j] -> per-wave LDS (b64 writes)
    #pragma unroll
    for (int jt = 0; jt < 4; ++jt) {
      float p0 = fexp2(sacc[jt][0]);
      float p1 = fexp2(sacc[jt][1]);
      float p2 = fexp2(sacc[jt][2]);
      float p3 = fexp2(sacc[jt][3]);
      lst += (p0 + p1) + (p2 + p3);
      union { uint32_t u[2]; uint64_t d; } pw;
      pw.u[0] = pktr(p0, p1);
      pw.u[1] = pktr(p2, p3);
      *(uint64_t*)&Pt[w][mi * 72 + jt * 16 + qd * 4] = pw.d;
    }

    asm volatile("s_waitcnt lgkmcnt(0)" ::: "memory");  // wave's P writes visible

    // O^T += V^T @ P^T  (K=32 MFMA; B-op = P rows read back b128)
    #pragma unroll
    for (int ktp = 0; ktp < 2; ++ktp) {
      bf16x8 pfx = *(const bf16x8*)&Pt[w][mi * 72 + ktp * 32 + qd * 8];
      #pragma unroll
      for (int dt = 0; dt < 4; ++dt) {
        bf16x8 vf = *(const bf16x8*)&Vs[par][fidx[dt][ktp]];
        oacc[dt] = __builtin_amdgcn_mfma_f32_16x16x32_bf16(vf, pfx, oacc[dt], 0, 0, 0);
      }
    }
  }

  // epilogue: finish l across quads, normalize, packed uint2 stores
  float l = lst;
  l += __shfl_xor(l, 16);
  l += __shfl_xor(l, 32);
  float inv = __builtin_amdgcn_rcpf(l);
  const int qg = qw + mi;
  bf16* cp = ctx + bTD + (size_t)qg * D_ + h * HD_ + qd * 4;
  #pragma unroll
  for (int dt = 0; dt < 4; ++dt) {
    union { bf16 o[4]; uint2 u; } pko;
    #pragma unroll
    for (int r = 0; r < 4; ++r) pko.o[r] = __float2bfloat16(oacc[dt][r] * inv);
    *(uint2*)(cp + dt * 16) = pko.u;
  }
}

// ---------------- launch ----------------
extern "C" void kernel_launch(void* const* d_in, const int* in_sizes, int n_in,
                              void* d_out, int out_size, void* d_ws, size_t ws_size,
                              hipStream_t stream) {
  const float* x  = (const float*)d_in[0];
  const float* Wq = (const float*)d_in[1];
  const float* Wk = (const float*)d_in[2];
  const float* Wv = (const float*)d_in[3];
  const float* Wo = (const float*)d_in[4];
  const float* bo = (const float*)d_in[5];
  float* out = (float*)d_out;

  char* ws = (char*)d_ws;
  const size_t SZ  = (size_t)M_ * D_ * 2;
  const size_t WSZ = (size_t)D_ * D_ * 2;
  bf16* xb   = (bf16*)(ws);                 // [M, D]
  bf16* Qb   = (bf16*)(ws + 1 * SZ);        // [B,T,D]
  bf16* Kb   = (bf16*)(ws + 2 * SZ);        // [B,T,D], pre-scaled by SCL
  bf16* Vtg  = (bf16*)(ws + 3 * SZ);        // [B][D][T]
  bf16* ctxb = (bf16*)(ws + 4 * SZ);        // [B,T,D]
  bf16* Wqb  = (bf16*)(ws + 5 * SZ);
  bf16* Wkb  = (bf16*)(ws + 5 * SZ + 1 * WSZ);
  bf16* Wvb  = (bf16*)(ws + 5 * SZ + 2 * WSZ);
  bf16* Wob  = (bf16*)(ws + 5 * SZ + 3 * WSZ);

  cvt_all<<<6144 + 4 * 576, 256, 0, stream>>>(x, Wq, Wk, Wv, Wo, xb, Wqb, Wkb, Wvb, Wob);

  gemm_qkv<<<1152, 256, 0, stream>>>(xb, Wqb, Wkb, Wvb, Qb, Kb, Vtg);

  flash_attn<<<(T_ / 128) * B_ * H_, 512, 0, stream>>>(Qb, Kb, Vtg, ctxb);

  gemm_out<<<384, 256, 0, stream>>>(ctxb, Wob, out, bo);
}